// Round 4
// baseline (190.629 us; speedup 1.0000x reference)
//
#include <hip/hip_runtime.h>
#include <hip/hip_bf16.h>

// D = 16, N = 50000 nodes, E = 800000 edges.
//
// Algebraic refactor of the reference:
//   out[n,o]  = bias[o] + sum_{u,v} x[n,u] * agg[n,v] * Wf[u,v,o]
//   agg[n,v]  = sum_{e: row_e=n} x[col_e,v]         (scatter-add of raw features)
//   Wf[u,v,o] = sum_w W_tp[u,v,w] * weight[o,w]     (built in-block, 4096 elems)
//
// Round-4 changes vs round-3 (which passed at 123 us, scatter_k=43 us):
//  - scatter uses packed v2f32 atomics (6.4M ops instead of 12.8M scalar);
//    round-3 WRITE_SIZE showed exactly 4B/atomic of fabric write traffic ->
//    testing whether the bound is op-rate (halves) or bytes (unchanged).
//  - bilinear register-blocks NT=4 nodes/thread -> sWf LDS read traffic /4
//    (was ~920 MB total, ~14 us LDS-bound).
//  - fuse_w folded into bilinear (each block rebuilds the 16.6 KB fused
//    weight from W_tp/weight: 272 FMA/thread, removes a dispatch).

#define D16 16
#define WF_STRIDE 260   // padded row stride: 260*4B = 1040 B, 16B-aligned, breaks bank aliasing
#define NT 4            // nodes per thread in bilinear
#define NB 64           // nodes per block = (256/16)*NT

typedef float v2f __attribute__((ext_vector_type(2)));

// ---- scatter: agg[row_e][2p..2p+1] += x[col_e][2p..2p+1], 8 threads per edge
__global__ __launch_bounds__(256) void scatter_k(const int* __restrict__ ei,
                                                 const float* __restrict__ x,
                                                 float* __restrict__ agg,
                                                 int E) {
    int t = blockIdx.x * 256 + threadIdx.x;
    if (t >= E * 8) return;
    int e = t >> 3;
    int p = t & 7;
    int r = ei[e];        // row   (broadcast across the 8 lanes of this edge)
    int c = ei[E + e];    // col
    v2f val = *(const v2f*)(&x[c * D16 + p * 2]);   // 8B coalesced gather
#if __has_builtin(__builtin_amdgcn_global_atomic_fadd_v2f32)
    __builtin_amdgcn_global_atomic_fadd_v2f32((v2f*)&agg[r * D16 + p * 2], val);
#else
    unsafeAtomicAdd(&agg[r * D16 + p * 2 + 0], val.x);
    unsafeAtomicAdd(&agg[r * D16 + p * 2 + 1], val.y);
#endif
}

// ---- per-node bilinear + fused linear, NT nodes per thread
__global__ __launch_bounds__(256) void bilinear_k(const float* __restrict__ x,
                                                  const float* __restrict__ agg,
                                                  const float* __restrict__ Wtp,
                                                  const float* __restrict__ wgt,
                                                  const float* __restrict__ bias,
                                                  float* __restrict__ out,
                                                  int N) {
    __shared__ float sWf[D16 * WF_STRIDE];  // 16.6 KB
    __shared__ float sx[NB * D16];          // 4 KB
    __shared__ float sa[NB * D16];          // 4 KB

    int t = threadIdx.x;

    // build fused weight in LDS: sWf[o*WF_STRIDE + uv] = sum_w Wtp[uv*16+w]*wgt[o*16+w]
    for (int i = t; i < D16 * WF_STRIDE; i += 256) {
        int o  = i / WF_STRIDE;
        int uv = i - o * WF_STRIDE;
        float acc = 0.f;
        if (uv < 256) {
#pragma unroll
            for (int w = 0; w < D16; ++w)
                acc = fmaf(Wtp[uv * D16 + w], wgt[o * D16 + w], acc);
        }
        sWf[i] = acc;
    }

    // stage x and agg for this block's NB nodes (zero-fill OOB)
    int nbase = blockIdx.x * NB;
    for (int i = t; i < NB * D16; i += 256) {
        int g = nbase * D16 + i;
        bool ok = g < N * D16;
        sx[i] = ok ? x[g] : 0.f;
        sa[i] = ok ? agg[g] : 0.f;
    }
    __syncthreads();

    int o   = t & 15;      // output feature
    int gq  = t >> 4;      // node group 0..15
    int nl0 = gq * NT;     // local node base

    float xv[NT][D16], av[NT][D16];
#pragma unroll
    for (int k = 0; k < NT; ++k)
#pragma unroll
        for (int i = 0; i < D16; ++i) {
            xv[k][i] = sx[(nl0 + k) * D16 + i];
            av[k][i] = sa[(nl0 + k) * D16 + i];
        }

    float b = bias[o];
    float acc[NT];
#pragma unroll
    for (int k = 0; k < NT; ++k) acc[k] = b;

    const float* wrow = &sWf[o * WF_STRIDE];
#pragma unroll
    for (int u = 0; u < D16; ++u) {
        float tu[NT] = {0.f, 0.f, 0.f, 0.f};
#pragma unroll
        for (int v = 0; v < D16; ++v) {          // consecutive v -> ds_read_b128
            float wv = wrow[u * D16 + v];
#pragma unroll
            for (int k = 0; k < NT; ++k)
                tu[k] = fmaf(av[k][v], wv, tu[k]);
        }
#pragma unroll
        for (int k = 0; k < NT; ++k)
            acc[k] = fmaf(xv[k][u], tu[k], acc[k]);
    }

#pragma unroll
    for (int k = 0; k < NT; ++k) {
        int n = nbase + nl0 + k;
        if (n < N) out[n * D16 + o] = acc[k];
    }
}

extern "C" void kernel_launch(void* const* d_in, const int* in_sizes, int n_in,
                              void* d_out, int out_size, void* d_ws, size_t ws_size,
                              hipStream_t stream) {
    const float* x    = (const float*)d_in[0];
    const int*   ei   = (const int*)d_in[1];
    const float* Wtp  = (const float*)d_in[2];
    const float* wgt  = (const float*)d_in[3];
    const float* bias = (const float*)d_in[4];
    float* out = (float*)d_out;

    int N = in_sizes[0] / D16;   // 50000
    int E = in_sizes[1] / 2;     // 800000

    float* agg = (float*)d_ws;   // N*16 floats

    // ws is poisoned 0xAA before every launch -> zero the accumulator
    hipMemsetAsync(agg, 0, (size_t)N * D16 * sizeof(float), stream);

    int sthreads = E * 8;        // 6.4M
    scatter_k<<<(sthreads + 255) / 256, 256, 0, stream>>>(ei, x, agg, E);

    int nblocks = (N + NB - 1) / NB;   // 782
    bilinear_k<<<nblocks, 256, 0, stream>>>(x, agg, Wtp, wgt, bias, out, N);
}